// Round 2
// baseline (243.110 us; speedup 1.0000x reference)
//
#include <hip/hip_runtime.h>
#include <stdint.h>
#include <stddef.h>

typedef float    f32x4 __attribute__((ext_vector_type(4)));
typedef float    f32x2 __attribute__((ext_vector_type(2)));
typedef _Float16 f16x2 __attribute__((ext_vector_type(2)));
typedef _Float16 f16x4 __attribute__((ext_vector_type(4)));
typedef _Float16 f16x8 __attribute__((ext_vector_type(8)));

#define HH 96
#define MROWS 16
#define NSTR 32      // noiseTD per-t stride in dwords (16 rows x float2)
#define OSTR 100     // outLDS row stride in dwords

// 16-lane-row sum via DPP (VALU, no DS): xor1, xor2 (quad_perm), ror4, ror8
#define DPP_ADD(v, ctrl) \
    ((v) + __builtin_bit_cast(float, __builtin_amdgcn_update_dpp( \
        0, __builtin_bit_cast(int, (v)), (ctrl), 0xF, 0xF, true)))

#define CVT_PK(a, b) __builtin_bit_cast(f16x2, __builtin_amdgcn_cvt_pkrtz((a), (b)))

__launch_bounds__(256, 2)
__global__ void policy_scan_kernel(
    const float* __restrict__ policy,     // (B,96,4)
    const float* __restrict__ noiseT,     // (B,96)
    const float* __restrict__ noiseD,     // (B,96)
    const float* __restrict__ action_pre, // (B,)
    const float* __restrict__ state_pre,  // (B,)
    const float* __restrict__ Lambda1,    // (1,)
    const float* __restrict__ Budget1,    // (1,)
    const float* __restrict__ W1,         // (256,6)
    const float* __restrict__ b1,         // (256,)
    const float* __restrict__ W2,         // (256,256)
    const float* __restrict__ b2,         // (256,)
    const float* __restrict__ W3,         // (256,)
    const float* __restrict__ b3,         // (1,)
    float* __restrict__ out)              // (B,96)
{
    __shared__ __attribute__((aligned(16))) float featLDS[HH*MROWS*4];   // 24576 B
    __shared__ __attribute__((aligned(16))) float noiseTD[HH*NSTR];      // 12288 B
    __shared__ __attribute__((aligned(16))) float partialLDS[2][MROWS*4];// 512 B, dbuf by t&1
    __shared__ __attribute__((aligned(16))) float tblLDS[HH*4];          // 1536 B
    __shared__ __attribute__((aligned(16))) float outLDS[MROWS*OSTR];    // 6400 B

    const int tid  = threadIdx.x;          // 0..255
    const int wave = tid >> 6;             // 0..3
    const int lane = tid & 63;
    const int l16  = lane & 15;
    const int lq   = lane >> 4;            // 0..3
    const int r0   = blockIdx.x * MROWS;

    // ---- stage inputs ----
    {
        const f32x4* src = (const f32x4*)(policy + (size_t)r0 * HH * 4);
        #pragma unroll
        for (int i = 0; i < 6; ++i) {
            int idx = i*256 + tid;                 // idx = row*96 + t
            int row = idx / 96, t = idx - row*96;
            *(f32x4*)&featLDS[(t*MROWS + row)*4] = src[idx];
        }
        const float* s1 = noiseT + (size_t)r0 * HH;
        const float* s2 = noiseD + (size_t)r0 * HH;
        #pragma unroll
        for (int i = 0; i < 6; ++i) {
            int idx = i*256 + tid;
            int row = idx / 96, t = idx - row*96;
            noiseTD[t*NSTR + row*2    ] = s1[idx];
            noiseTD[t*NSTR + row*2 + 1] = s2[idx];
        }
    }
    const float lam  = Lambda1[0];
    const float budH = Budget1[0] * (1.0f/96.0f);
    const float b3s  = b3[0];
    const float per_step = lam * 2.0f + budH;
    if (tid < HH) {
        float e  = __builtin_exp2f(-2.0f * (float)(95 - tid));
        float ft = 0.5f * (1.0f - e);
        float G  = 2.0f + ft;
        *(f32x4*)&tblLDS[tid*4] = f32x4{ft, G, 1.0f/G, lam*2.0f + budH*((float)tid + 2.0f)};
    }

    // ---- W2 -> fp16 B-frags, k-PERMUTED to match register-resident layer-1 output ----
    // A-side (phase B) lane (l16,g) slot j holds h1[n1][l16] with
    //   n1(kc,g,j) = (2kc + (j>>2))*16 + g*4 + (j&3)
    // so B-frag bfr[tt][kc] slot (g=lq, j) = W2[n_out, n1(kc,lq,j)]:
    //   j=0..3 -> wrow[kc*32 + lq*4 + j], j=4..7 -> wrow[kc*32 + 16 + lq*4 + (j-4)]
    f16x8 bfr[4][8];
    float b2v[4], w3v[4];
    #pragma unroll
    for (int tt = 0; tt < 4; ++tt) {
        const int n = wave*64 + tt*16 + l16;
        const float* wrow = W2 + (size_t)n * 256;
        #pragma unroll
        for (int kc = 0; kc < 8; ++kc) {
            f32x4 u0 = *(const f32x4*)(wrow + kc*32 + lq*4);
            f32x4 u1 = *(const f32x4*)(wrow + kc*32 + 16 + lq*4);
            f16x8 v;
            v[0]=(_Float16)u0[0]; v[1]=(_Float16)u0[1]; v[2]=(_Float16)u0[2]; v[3]=(_Float16)u0[3];
            v[4]=(_Float16)u1[0]; v[5]=(_Float16)u1[1]; v[6]=(_Float16)u1[2]; v[7]=(_Float16)u1[3];
            bfr[tt][kc] = v;
        }
        b2v[tt] = b2[n];
        w3v[tt] = W3[n];
    }

    // ---- W1 as 16x16x16 A-frags: 16 tiles cover ALL 256 neurons (replicated per wave) ----
    // lane (l16,g) holds A[m'=l16][k=g*4+j]; K=7 (6 inputs + bias at k=6)
    f16x4 w1A[16];
    #pragma unroll
    for (int q2 = 0; q2 < 16; ++q2) {
        f16x4 w = {};
        const int nn = q2*16 + l16;
        if (lq == 0) {
            w[0]=(_Float16)W1[nn*6+0]; w[1]=(_Float16)W1[nn*6+1];
            w[2]=(_Float16)W1[nn*6+2]; w[3]=(_Float16)W1[nn*6+3];
        } else if (lq == 1) {
            w[0]=(_Float16)W1[nn*6+4]; w[1]=(_Float16)W1[nn*6+5];
            w[2]=(_Float16)b1[nn];     // bias at k=6, xB k=6 carries 1.0
        }
        w1A[q2] = w;
    }

    // ---- recurrence state: lane owns row l16 (replicated across lq/wave) ----
    float stA = action_pre[r0 + l16];
    float stS = state_pre[r0 + l16];
    float stB = per_step, stC = 0.0f, stSS = 0.0f, stAD = 0.0f;
    __syncthreads();

    #pragma unroll 1
    for (int t = 0; t < HH; ++t) {
        // read-only LDS loads issued early (hidden under MFMAs); tb/nz used post-barrier
        const f32x4 f  = *(const f32x4*)&featLDS[(t*MROWS + l16)*4];
        const f32x4 tb = *(const f32x4*)&tblLDS[t*4];
        const f32x2 nz = *(const f32x2*)&noiseTD[t*NSTR + l16*2];
        const float dem = f[0];

        // x as 16x16x16 B-frag: lane (l16,g) holds B[k=g*4+j][n=l16]
        f16x4 xB = {};
        if (lq == 0) {
            xB[0]=(_Float16)f[0]; xB[1]=(_Float16)f[1];
            xB[2]=(_Float16)f[2]; xB[3]=(_Float16)f[3];
        } else if (lq == 1) {
            xB[0]=(_Float16)stA; xB[1]=(_Float16)stS; xB[2]=(_Float16)1.0f;
        }

        // b2 bias folded into accumulator init (D col = n = l16, same for all r)
        f32x4 acc[4];
        #pragma unroll
        for (int tt = 0; tt < 4; ++tt)
            acc[tt] = f32x4{b2v[tt], b2v[tt], b2v[tt], b2v[tt]};

        // ---- fused layer1 (registers, replicated) + layer2, NO LDS, NO barrier ----
        #pragma unroll
        for (int kc = 0; kc < 8; ++kc) {
            const f32x4 z = {0.f, 0.f, 0.f, 0.f};
            f32x4 g0 = __builtin_amdgcn_mfma_f32_16x16x16f16(w1A[2*kc    ], xB, z, 0, 0, 0);
            f32x4 g1 = __builtin_amdgcn_mfma_f32_16x16x16f16(w1A[2*kc + 1], xB, z, 0, 0, 0);
            // pack + relu: cvt_pkrtz pairs, then packed f16 max (relu commutes with RTZ)
            f16x2 c0 = CVT_PK(g0[0], g0[1]);
            f16x2 c1 = CVT_PK(g0[2], g0[3]);
            f16x2 c2 = CVT_PK(g1[0], g1[1]);
            f16x2 c3 = CVT_PK(g1[2], g1[3]);
            f16x8 h = {c0[0],c0[1],c1[0],c1[1],c2[0],c2[1],c3[0],c3[1]};
            const f16x8 hz = {};
            h = __builtin_elementwise_max(h, hz);
            #pragma unroll
            for (int tt = 0; tt < 4; ++tt)
                acc[tt] = __builtin_amdgcn_mfma_f32_16x16x32_f16(h, bfr[tt][kc], acc[tt], 0, 0, 0);
        }

        // ---- layer3 dot + 16-lane DPP reduce; partial exchange (dbuf by t&1) ----
        #pragma unroll
        for (int r = 0; r < 4; ++r) {
            float s0 = fmaf(w3v[0], fmaxf(acc[0][r], 0.0f), w3v[1] * fmaxf(acc[1][r], 0.0f));
            float s1 = fmaf(w3v[2], fmaxf(acc[2][r], 0.0f), w3v[3] * fmaxf(acc[3][r], 0.0f));
            float v = s0 + s1;
            v = DPP_ADD(v, 0xB1);    // quad_perm [1,0,3,2]  (xor 1)
            v = DPP_ADD(v, 0x4E);    // quad_perm [2,3,0,1]  (xor 2)
            v = DPP_ADD(v, 0x124);   // row_ror:4
            v = DPP_ADD(v, 0x128);   // row_ror:8 -> full row sum in all lanes
            if (l16 == 0) partialLDS[t & 1][(lq*4 + r)*4 + wave] = v;   // [m][w]
        }
        __syncthreads();   // the ONLY barrier per t

        // ---- recurrence for row l16 (replicated in all lanes) ----
        // dbuf safety: buf[t&1] reads here precede the next barrier; the next write to
        // buf[t&1] is at t+2, after barrier t+1 -> no WAR race.
        const f32x4 q = *(const f32x4*)&partialLDS[t & 1][l16*4];        // w=0..3
        float psum = (q[0] + q[1]) + (q[2] + q[3]);
        float a_ml   = fmaxf(psum + b3s, 0.0f);
        float a_prior = fminf(fmaxf(stS + dem, 0.0f) * 1.25f, 10.0f);
        float sgn    = (a_ml < a_prior) ? 1.0f : -1.0f;
        float a_out  = fmaf(fmaxf(fabsf(a_ml - a_prior) - stB * tb[2], 0.0f), sgn, a_ml);
        float ns     = fminf(fmaxf(stS * (1.0f - nz[1]) + dem - (0.8f + nz[0]) * a_out, 0.0f), 15.0f);
        float c_cost = fmaf(fmaf(0.1f, ns, 1.0f), ns, 2.0f);
        float ad_new = fabsf(a_out - a_prior);
        float cum_dv = fmaf(2.0f, ad_new, 0.375f * stSS);
        float c_prior = fmaxf(2.0f, c_cost - cum_dv);
        float cum_c_new = stC + (1.0f + lam) * c_prior - c_cost;
        float T      = fmaf(0.25f, stSS, ad_new);
        float cum_dg = tb[0] * T;
        float bgt_if = fmaxf(fmaxf(stB + per_step - ad_new * tb[1], 0.0f),
                             cum_c_new - cum_dg + tb[3]);
        float bgt_else = fmaxf(stB + per_step - stAD * tb[1], 0.0f);
        if (t == HH - 1) { stB = bgt_else; }
        else             { stB = bgt_if; stC = cum_c_new; }
        stSS = T;
        stAD = ad_new;
        stA  = a_out;
        stS  = ns;
        if (tid < MROWS) outLDS[tid*OSTR + t] = a_out;
    }

    // ---- coalesced output dump ----
    __syncthreads();
    float* oslice = out + (size_t)r0 * HH;
    #pragma unroll
    for (int i = 0; i < 3; ++i) {
        int idx = (i*256 + tid) * 2;               // 1536 dwords total
        int row = idx / 96, c = idx - row*96;      // pairs never straddle rows (96 even)
        f32x2 v = { outLDS[row*OSTR + c], outLDS[row*OSTR + c + 1] };
        *(f32x2*)&oslice[idx] = v;
    }
}

extern "C" void kernel_launch(void* const* d_in, const int* in_sizes, int n_in,
                              void* d_out, int out_size, void* d_ws, size_t ws_size,
                              hipStream_t stream) {
    policy_scan_kernel<<<dim3(8192 / MROWS), dim3(256), 0, stream>>>(
        (const float*)d_in[0],  // policy_in_c
        (const float*)d_in[1],  // trans_noise
        (const float*)d_in[2],  // demand_noise
        (const float*)d_in[3],  // action_pre
        (const float*)d_in[4],  // state_pre
        (const float*)d_in[5],  // Lambda
        (const float*)d_in[6],  // Budget
        (const float*)d_in[7],  // W1
        (const float*)d_in[8],  // b1
        (const float*)d_in[9],  // W2
        (const float*)d_in[10], // b2
        (const float*)d_in[11], // W3
        (const float*)d_in[12], // b3
        (float*)d_out);
}

// Round 3
// 226.821 us; speedup vs baseline: 1.0718x; 1.0718x over previous
//
#include <hip/hip_runtime.h>
#include <stdint.h>
#include <stddef.h>

typedef float    f32x4 __attribute__((ext_vector_type(4)));
typedef float    f32x2 __attribute__((ext_vector_type(2)));
typedef _Float16 f16x4 __attribute__((ext_vector_type(4)));
typedef _Float16 f16x8 __attribute__((ext_vector_type(8)));

#define HH 96
#define MROWS 16
#define OCT 136      // h1 A-layout oct stride in halves (272 B)
#define NSTR 32      // noiseTD per-t stride in dwords (16 rows x float2)
#define OSTR 100     // outLDS row stride in dwords

// 16-lane-row sum via DPP (VALU, no DS): xor1, xor2 (quad_perm), ror4, ror8
#define DPP_ADD(v, ctrl) \
    ((v) + __builtin_bit_cast(float, __builtin_amdgcn_update_dpp( \
        0, __builtin_bit_cast(int, (v)), (ctrl), 0xF, 0xF, true)))

__launch_bounds__(256, 2)
__global__ void policy_scan_kernel(
    const float* __restrict__ policy,     // (B,96,4)
    const float* __restrict__ noiseT,     // (B,96)
    const float* __restrict__ noiseD,     // (B,96)
    const float* __restrict__ action_pre, // (B,)
    const float* __restrict__ state_pre,  // (B,)
    const float* __restrict__ Lambda1,    // (1,)
    const float* __restrict__ Budget1,    // (1,)
    const float* __restrict__ W1,         // (256,6)
    const float* __restrict__ b1,         // (256,)
    const float* __restrict__ W2,         // (256,256)
    const float* __restrict__ b2,         // (256,)
    const float* __restrict__ W3,         // (256,)
    const float* __restrict__ b3,         // (1,)
    float* __restrict__ out)              // (B,96)
{
    __shared__ __attribute__((aligned(16))) float    featLDS[HH*MROWS*4];  // [t][row][4] 24576 B
    __shared__ __attribute__((aligned(16))) float    noiseTD[HH*NSTR];     // [t][row][2] 12288 B
    __shared__ __attribute__((aligned(16))) _Float16 h1LDS[32*OCT];        // 8704 B
    __shared__ __attribute__((aligned(16))) float    partialLDS[MROWS*4];  // [m][w] 256 B
    __shared__ __attribute__((aligned(16))) float    tblLDS[HH*4];         // [t]{ft,Gam,invG,bcoef}
    __shared__ __attribute__((aligned(16))) float    outLDS[MROWS*OSTR];   // 6400 B

    const int tid  = threadIdx.x;          // 0..255
    const int wave = tid >> 6;             // 0..3
    const int lane = tid & 63;
    const int l16  = lane & 15;
    const int lq   = lane >> 4;            // 0..3
    const int r0   = blockIdx.x * MROWS;

    // ---- stage inputs ----
    {
        const f32x4* src = (const f32x4*)(policy + (size_t)r0 * HH * 4);
        #pragma unroll
        for (int i = 0; i < 6; ++i) {
            int idx = i*256 + tid;                 // idx = row*96 + t
            int row = idx / 96, t = idx - row*96;
            *(f32x4*)&featLDS[(t*MROWS + row)*4] = src[idx];
        }
        const float* s1 = noiseT + (size_t)r0 * HH;
        const float* s2 = noiseD + (size_t)r0 * HH;
        #pragma unroll
        for (int i = 0; i < 6; ++i) {
            int idx = i*256 + tid;
            int row = idx / 96, t = idx - row*96;
            noiseTD[t*NSTR + row*2    ] = s1[idx];
            noiseTD[t*NSTR + row*2 + 1] = s2[idx];
        }
    }
    const float lam  = Lambda1[0];
    const float budH = Budget1[0] * (1.0f/96.0f);
    const float b3s  = b3[0];
    const float per_step = lam * 2.0f + budH;
    if (tid < HH) {
        float e  = __builtin_exp2f(-2.0f * (float)(95 - tid));
        float ft = 0.5f * (1.0f - e);
        float G  = 2.0f + ft;
        *(f32x4*)&tblLDS[tid*4] = f32x4{ft, G, 1.0f/G, lam*2.0f + budH*((float)tid + 2.0f)};
    }

    // ---- W2 -> fp16 B-frags: 4 n-tiles/wave (128 VGPR) ----
    // tile tt covers n = wave*64 + tt*16 + l16 ; k = kc*32 + lq*8 + j
    f16x8 bfr[4][8];
    float b2v[4], w3v[4];
    #pragma unroll
    for (int tt = 0; tt < 4; ++tt) {
        const int n = wave*64 + tt*16 + l16;
        const float* wrow = W2 + (size_t)n * 256;
        #pragma unroll
        for (int kc = 0; kc < 8; ++kc) {
            const int k0 = kc*32 + lq*8;
            f32x4 u0 = *(const f32x4*)(wrow + k0);
            f32x4 u1 = *(const f32x4*)(wrow + k0 + 4);
            f16x8 v;
            v[0]=(_Float16)u0[0]; v[1]=(_Float16)u0[1]; v[2]=(_Float16)u0[2]; v[3]=(_Float16)u0[3];
            v[4]=(_Float16)u1[0]; v[5]=(_Float16)u1[1]; v[6]=(_Float16)u1[2]; v[7]=(_Float16)u1[3];
            bfr[tt][kc] = v;
        }
        b2v[tt] = b2[n];
        w3v[tt] = W3[n];
    }

    // ---- W1 as MFMA A-frags for h1^T = W1.x^T (bias folded at k=6) ----
    f16x8 w1A[4];
    #pragma unroll
    for (int tt = 0; tt < 4; ++tt) {
        f16x8 w = {};
        if (lq == 0) {
            const int nn = wave*64 + tt*16 + l16;   // A row m' = l16 -> neuron
            #pragma unroll
            for (int j = 0; j < 6; ++j) w[j] = (_Float16)W1[nn*6 + j];
            w[6] = (_Float16)b1[nn];
        }
        w1A[tt] = w;
    }

    // h1 write: value (tt,r) -> k = wave*64+tt*16+lq*4+r, m = l16
    // addr(halves) = (k>>3)*OCT + m*8 + (k&7); r=0..3 contiguous -> b64
    const int h1wbase = (wave*8 + (lq>>1))*OCT + l16*8 + (lq&1)*4;
    const int h1r     = lq*OCT + l16*8;          // + kc*(4*OCT)

    // ---- recurrence state: lane owns row l16 (replicated across lq/wave) ----
    float stA = action_pre[r0 + l16];
    float stS = state_pre[r0 + l16];
    float stB = per_step, stC = 0.0f, stSS = 0.0f, stAD = 0.0f;
    __syncthreads();

    // ---- anti-phase stagger: co-resident pairs differ by 256 (b%8->XCD, b/8->CU slot).
    // Skew one member by ~half a per-t period (~2048 cy) so its MFMA region overlaps the
    // partner's VALU region; equal per-t periods keep the offset for all 96 steps.
    if ((blockIdx.x >> 8) & 1) {
        #pragma unroll
        for (int i = 0; i < 32; ++i) __builtin_amdgcn_s_sleep(1);
    }

    #pragma unroll 1
    for (int t = 0; t < HH; ++t) {
        // ---- Phase A: layer 1 via MFMA, h1^T orientation ----
        f32x4 f = *(const f32x4*)&featLDS[(t*MROWS + l16)*4];
        float dem = f[0];
        f16x8 xB = {};
        if (lq == 0) {
            xB[0]=(_Float16)f[0]; xB[1]=(_Float16)f[1];
            xB[2]=(_Float16)f[2]; xB[3]=(_Float16)f[3];
            xB[4]=(_Float16)stA;  xB[5]=(_Float16)stS;
            xB[6]=(_Float16)1.0f;
        }
        #pragma unroll
        for (int tt = 0; tt < 4; ++tt) {
            f32x4 g = {0.f,0.f,0.f,0.f};
            g = __builtin_amdgcn_mfma_f32_16x16x32_f16(w1A[tt], xB, g, 0, 0, 0);
            f16x4 hv;
            #pragma unroll
            for (int r = 0; r < 4; ++r) hv[r] = (_Float16)fmaxf(g[r], 0.0f);
            *(f16x4*)&h1LDS[h1wbase + tt*(2*OCT)] = hv;    // ds_write_b64
        }
        __syncthreads();   // bar1: h1 complete

        // ---- Phase B: layer 2, A-frag shared across 4 n-tiles; b2 folded into acc init ----
        f32x4 acc[4];
        #pragma unroll
        for (int tt = 0; tt < 4; ++tt) acc[tt] = f32x4{b2v[tt], b2v[tt], b2v[tt], b2v[tt]};
        #pragma unroll
        for (int kc = 0; kc < 8; ++kc) {
            f16x8 a = *(const f16x8*)&h1LDS[h1r + kc*(4*OCT)];
            #pragma unroll
            for (int tt = 0; tt < 4; ++tt)
                acc[tt] = __builtin_amdgcn_mfma_f32_16x16x32_f16(a, bfr[tt][kc], acc[tt], 0, 0, 0);
        }

        // ---- Phase C: relu, dot W3; 16-lane reduce via DPP (VALU only) ----
        #pragma unroll
        for (int r = 0; r < 4; ++r) {
            float s0 = fmaf(w3v[0], fmaxf(acc[0][r], 0.0f), w3v[1] * fmaxf(acc[1][r], 0.0f));
            float s1 = fmaf(w3v[2], fmaxf(acc[2][r], 0.0f), w3v[3] * fmaxf(acc[3][r], 0.0f));
            float v = s0 + s1;
            v = DPP_ADD(v, 0xB1);    // quad_perm [1,0,3,2]  (xor 1)
            v = DPP_ADD(v, 0x4E);    // quad_perm [2,3,0,1]  (xor 2)
            v = DPP_ADD(v, 0x124);   // row_ror:4
            v = DPP_ADD(v, 0x128);   // row_ror:8 -> full row sum in all lanes
            if (l16 == 0) partialLDS[(lq*4 + r)*4 + wave] = v;   // [m][w]
        }
        __syncthreads();   // bar2: partials complete

        // ---- Phase D: recurrence for row l16 (replicated) ----
        f32x4 q  = *(const f32x4*)&partialLDS[l16*4];            // w=0..3
        f32x4 tb = *(const f32x4*)&tblLDS[t*4];                  // wave-uniform
        f32x2 nz = *(const f32x2*)&noiseTD[t*NSTR + l16*2];
        float psum = (q[0] + q[1]) + (q[2] + q[3]);
        float a_ml   = fmaxf(psum + b3s, 0.0f);
        float a_prior = fminf(fmaxf(stS + dem, 0.0f) * 1.25f, 10.0f);
        float sgn    = (a_ml < a_prior) ? 1.0f : -1.0f;
        float a_out  = fmaf(fmaxf(fabsf(a_ml - a_prior) - stB * tb[2], 0.0f), sgn, a_ml);
        float ns     = fminf(fmaxf(stS * (1.0f - nz[1]) + dem - (0.8f + nz[0]) * a_out, 0.0f), 15.0f);
        float c_cost = fmaf(fmaf(0.1f, ns, 1.0f), ns, 2.0f);
        float ad_new = fabsf(a_out - a_prior);
        float cum_dv = fmaf(2.0f, ad_new, 0.375f * stSS);
        float c_prior = fmaxf(2.0f, c_cost - cum_dv);
        float cum_c_new = stC + (1.0f + lam) * c_prior - c_cost;
        float T      = fmaf(0.25f, stSS, ad_new);
        float cum_dg = tb[0] * T;
        float bgt_if = fmaxf(fmaxf(stB + per_step - ad_new * tb[1], 0.0f),
                             cum_c_new - cum_dg + tb[3]);
        float bgt_else = fmaxf(stB + per_step - stAD * tb[1], 0.0f);
        if (t == HH - 1) { stB = bgt_else; }
        else             { stB = bgt_if; stC = cum_c_new; }
        stSS = T;
        stAD = ad_new;
        stA  = a_out;
        stS  = ns;
        if (tid < MROWS) outLDS[tid*OSTR + t] = a_out;
        // no barrier: D's reads are bar2-protected; A(t+1) writes race-free (see r4 proof)
    }

    // ---- coalesced output dump ----
    __syncthreads();
    float* oslice = out + (size_t)r0 * HH;
    #pragma unroll
    for (int i = 0; i < 3; ++i) {
        int idx = (i*256 + tid) * 2;               // 1536 dwords total
        int row = idx / 96, c = idx - row*96;      // pairs never straddle rows (96 even)
        f32x2 v = { outLDS[row*OSTR + c], outLDS[row*OSTR + c + 1] };
        *(f32x2*)&oslice[idx] = v;
    }
}

extern "C" void kernel_launch(void* const* d_in, const int* in_sizes, int n_in,
                              void* d_out, int out_size, void* d_ws, size_t ws_size,
                              hipStream_t stream) {
    policy_scan_kernel<<<dim3(8192 / MROWS), dim3(256), 0, stream>>>(
        (const float*)d_in[0],  // policy_in_c
        (const float*)d_in[1],  // trans_noise
        (const float*)d_in[2],  // demand_noise
        (const float*)d_in[3],  // action_pre
        (const float*)d_in[4],  // state_pre
        (const float*)d_in[5],  // Lambda
        (const float*)d_in[6],  // Budget
        (const float*)d_in[7],  // W1
        (const float*)d_in[8],  // b1
        (const float*)d_in[9],  // W2
        (const float*)d_in[10], // b2
        (const float*)d_in[11], // W3
        (const float*)d_in[12], // b3
        (float*)d_out);
}